// Round 9
// baseline (132.362 us; speedup 1.0000x reference)
//
#include <hip/hip_runtime.h>
#include <hip/hip_bf16.h>

// Pipeline: weight prep -> q cast + im2col cast of x -> qproj GEMM ->
//           conv-as-GEMM (A=xim bf16, split-K=4, partials in d_out) ->
//           fused reduce+bias+LN -> kvproj GEMM -> fused attention -> out proj.
// GEMM v3: T3-min 2-phase pipeline with __builtin_amdgcn_global_load_lds
//   (width 16, pre-swizzled per-lane global source, linear LDS dest,
//   one __syncthreads per K-step = vmcnt(0) drain) + XCD-chunked swizzle.
// Attention v6: head->XCD pinning (head = bid&7 so each XCD's L2 holds ONE
//   head's K/V = 512KB, L2-resident) + sched_barrier(0) pinning the 2-deep
//   register prefetch ring against scheduler sinking.
// Workspace requirement: ~68 MB.

using bf16 = __hip_bfloat16;
using f32x4 = __attribute__((ext_vector_type(4))) float;
using bf16x8 = __attribute__((ext_vector_type(8))) short;

#define DEVINL __device__ __forceinline__
#define AS1 __attribute__((address_space(1)))
#define AS3 __attribute__((address_space(3)))

DEVINL f32x4 mfma16(bf16x8 a, bf16x8 b, f32x4 c) {
    return __builtin_amdgcn_mfma_f32_16x16x32_bf16(a, b, c, 0, 0, 0);
}

DEVINL unsigned short f2bf(float f) {
    union { float f; unsigned u; } x; x.f = f;
    unsigned u = x.u;
    u += 0x7fffu + ((u >> 16) & 1u);   // RNE
    return (unsigned short)(u >> 16);
}

// pack two f32 -> two bf16 (RTZ) in one v_perm: low16 = trunc(a), high16 = trunc(b)
DEVINL unsigned pk_rtz(float a, float b) {
    return __builtin_amdgcn_perm(__float_as_uint(b), __float_as_uint(a), 0x07060302u);
}

DEVINL float ex2(float x) { return __builtin_amdgcn_exp2f(x); }   // raw v_exp_f32

// async global->LDS DMA, 16B per lane. lds dest must be wave-uniform base
// (HW deposits at base + lane*16). CK-style addrspace reinterpret casts.
DEVINL void gl16(const bf16* g, bf16* l) {
    __builtin_amdgcn_global_load_lds(
        (const AS1 void*)(unsigned long long)(uintptr_t)g,
        (AS3 void*)(unsigned)(uintptr_t)l,
        16, 0, 0);
}

// ---------------- prep kernels ----------------

// f32 -> bf16, 8 elems/thread
__global__ __launch_bounds__(256) void cast_bf16_kernel(const float* __restrict__ in,
                                                        bf16* __restrict__ out, int n8) {
    int i = blockIdx.x * 256 + threadIdx.x;
    if (i >= n8) return;
    float4 a = ((const float4*)in)[i * 2];
    float4 b = ((const float4*)in)[i * 2 + 1];
    uint4 u;
    u.x = f2bf(a.x) | ((unsigned)f2bf(a.y) << 16);
    u.y = f2bf(a.z) | ((unsigned)f2bf(a.w) << 16);
    u.z = f2bf(b.x) | ((unsigned)f2bf(b.y) << 16);
    u.w = f2bf(b.z) | ((unsigned)f2bf(b.w) << 16);
    ((uint4*)out)[i] = u;
}

// im2col + cast: xim[pr][dydx*256+c] = x[b][(ii*4+dy)*128 + jj*4+dx][c]  (bf16)
__global__ __launch_bounds__(256) void im2col_kernel(const float* __restrict__ x,
                                                     bf16* __restrict__ xim) {
    int m = blockIdx.x * 256 + threadIdx.x;    // chunk id: pr*512 + dydx*32 + cchunk
    int cc8 = (m & 31) << 3;
    int dydx = (m >> 5) & 15;
    int pr = m >> 9;
    int b = pr >> 10, pi = pr & 1023;
    int ii = pi >> 5, jj = pi & 31;
    int dy = dydx >> 2, dx = dydx & 3;
    int pos = ((ii << 2) + dy) * 128 + (jj << 2) + dx;
    const float* s = &x[(size_t)((b << 14) + pos) * 256 + cc8];
    float4 a = *(const float4*)s;
    float4 c = *(const float4*)(s + 4);
    uint4 u;
    u.x = f2bf(a.x) | ((unsigned)f2bf(a.y) << 16);
    u.y = f2bf(a.z) | ((unsigned)f2bf(a.w) << 16);
    u.z = f2bf(c.x) | ((unsigned)f2bf(c.y) << 16);
    u.w = f2bf(c.z) | ((unsigned)f2bf(c.w) << 16);
    *(uint4*)&xim[(size_t)m * 8] = u;
}

// out[n*K + k] = in[k*N + n]  (weight [K,N] -> [N,K] bf16)
__global__ __launch_bounds__(256) void transpose_cast_kernel(const float* __restrict__ in,
                                                             bf16* __restrict__ out, int K, int N) {
    int idx = blockIdx.x * 256 + threadIdx.x;
    if (idx >= K * N) return;
    int k = idx % K, n = idx / K;
    out[idx] = __float2bfloat16(in[k * N + n]);
}

// wcv[o*4096 + dydx*256 + c] = sr_w[o][c][dy][dx]   (OIHW, 4x4)
__global__ __launch_bounds__(256) void conv_w_kernel(const float* __restrict__ sr_w,
                                                     bf16* __restrict__ out) {
    int idx = blockIdx.x * 256 + threadIdx.x;   // exact grid: 4096*256 = 1048576
    int o = idx >> 12, rest = idx & 4095, dydx = rest >> 8, c = rest & 255;
    out[idx] = __float2bfloat16(sr_w[((o << 8) + c) * 16 + dydx]);
}

// ---------------- GEMM (all-bf16, global_load_lds 2-phase) ----------------
template<int EMODE>
__global__ __launch_bounds__(256, 4) void gemm_kernel(
    const bf16* __restrict__ A, const bf16* __restrict__ WT,
    const float* __restrict__ bias,
    bf16* __restrict__ outb, float* __restrict__ outf, bf16* __restrict__ out2,
    int M, int N, int K, int KS)
{
    __shared__ alignas(16) bf16 As[2][64 * 64];
    __shared__ alignas(16) bf16 Bs[2][64 * 64];
    // XCD-chunked swizzle: XCD (bx%8) gets a contiguous tm-range with all tn.
    const int cpx = gridDim.x >> 3;
    const int bx = (blockIdx.x & 7) * cpx + (blockIdx.x >> 3);
    const int ntn = N >> 6;
    const int tm = bx / ntn, tn = bx % ntn;
    const int tid = threadIdx.x, lane = tid & 63, wid = tid >> 6;
    const int l15 = lane & 15, g = lane >> 4;
    const int wm = (wid >> 1) << 5, wn = (wid & 1) << 5;
    f32x4 acc[2][2] = {};

    int r_[2], cs_[2];
#pragma unroll
    for (int j = 0; j < 2; ++j) {
        int idx = (wid * 2 + j) * 64 + lane;
        r_[j] = idx >> 3;
        cs_[j] = ((idx & 7) ^ (r_[j] & 7)) << 3;   // pre-swizzled source column
    }
    const bf16* Arow = &A[(size_t)(tm * 64) * K];
    const bf16* Brow = &WT[(size_t)(tn * 64) * K];

    const int kbeg = blockIdx.y * KS;
    const int nsteps = KS >> 6;

    auto stage = [&](int buf, int k0) {
#pragma unroll
        for (int j = 0; j < 2; ++j) {
            gl16(Arow + (size_t)r_[j] * K + (k0 + cs_[j]), &As[buf][(wid * 2 + j) * 512]);
            gl16(Brow + (size_t)r_[j] * K + (k0 + cs_[j]), &Bs[buf][(wid * 2 + j) * 512]);
        }
    };

    stage(0, kbeg);
    __syncthreads();                     // vmcnt(0) drain + barrier

    for (int t = 0; t < nsteps; ++t) {
        const int buf = t & 1;
        if (t + 1 < nsteps) stage(buf ^ 1, kbeg + (t + 1) * 64);  // in flight across compute
#pragma unroll
        for (int kk = 0; kk < 2; ++kk) {
            const int sw = l15 & 7;
            const int co = ((kk * 4 + g) ^ sw) << 3;
            bf16x8 a0 = *(const bf16x8*)&As[buf][(wm + l15) * 64 + co];
            bf16x8 a1 = *(const bf16x8*)&As[buf][(wm + 16 + l15) * 64 + co];
            bf16x8 b0 = *(const bf16x8*)&Bs[buf][(wn + l15) * 64 + co];
            bf16x8 b1 = *(const bf16x8*)&Bs[buf][(wn + 16 + l15) * 64 + co];
            acc[0][0] = mfma16(a0, b0, acc[0][0]);
            acc[0][1] = mfma16(a0, b1, acc[0][1]);
            acc[1][0] = mfma16(a1, b0, acc[1][0]);
            acc[1][1] = mfma16(a1, b1, acc[1][1]);
        }
        __syncthreads();
    }

    const float qscale = 0.1767766953f * 1.4426950409f;  // HD^-0.5 * log2(e)
#pragma unroll
    for (int mi = 0; mi < 2; ++mi)
#pragma unroll
    for (int ni = 0; ni < 2; ++ni)
#pragma unroll
    for (int r = 0; r < 4; ++r) {
        int row = tm * 64 + wm + mi * 16 + g * 4 + r;
        int col = tn * 64 + wn + ni * 16 + l15;
        float v = acc[mi][ni][r];
        if constexpr (EMODE == 0) {
            outb[(size_t)row * 256 + col] = __float2bfloat16(v * qscale);
        } else if constexpr (EMODE == 1) {
            outf[(size_t)row * 256 + col] = v + bias[col];
        } else if constexpr (EMODE == 2) {
            int bb = row >> 10, key = row & 1023;
            if (col < 256) {
                int hh = col >> 5, d = col & 31;
                outb[(size_t)(((bb << 3) + hh) * 1024 + key) * 32 + d] = __float2bfloat16(v);
            } else {
                int d = col - 256;
                // key-permuted position within its 32-block: PV B-fragment order
                int c = key & 31;
                int pos = (((c >> 2) & 3) << 3) + ((c >> 4) << 2) + (c & 3);
                int keyp = (key & ~31) | pos;
                out2[(size_t)(((bb << 3) + (d >> 5)) * 32 + (d & 31)) * 1024 + keyp] =
                    __float2bfloat16(v);
            }
        } else {
            outf[((size_t)blockIdx.y * 4096 + row) * 256 + col] = v;
        }
    }
}

// ------- fused split-K reduce + conv bias + LayerNorm (C=256, one wave/row) -------
__global__ __launch_bounds__(256) void ln_kernel(const float* __restrict__ pp,
                                                 const float* __restrict__ cb,
                                                 const float* __restrict__ gw,
                                                 const float* __restrict__ bw,
                                                 bf16* __restrict__ out) {
    int row = blockIdx.x * 4 + (threadIdx.x >> 6);
    int lane = threadIdx.x & 63;
    const size_t base = (size_t)row * 256 + lane * 4;
    float4 v = *(const float4*)&pp[base];
#pragma unroll
    for (int s = 1; s < 4; ++s) {
        const float4 t = *(const float4*)&pp[(size_t)s * (4096 * 256) + base];
        v.x += t.x; v.y += t.y; v.z += t.z; v.w += t.w;
    }
    const float4 cbv = *(const float4*)&cb[lane * 4];
    v.x += cbv.x; v.y += cbv.y; v.z += cbv.z; v.w += cbv.w;

    float s = v.x + v.y + v.z + v.w;
#pragma unroll
    for (int m = 1; m < 64; m <<= 1) s += __shfl_xor(s, m, 64);
    float mu = s * 0.00390625f;
    float d0 = v.x - mu, d1 = v.y - mu, d2 = v.z - mu, d3 = v.w - mu;
    float qv = d0 * d0 + d1 * d1 + d2 * d2 + d3 * d3;
#pragma unroll
    for (int m = 1; m < 64; m <<= 1) qv += __shfl_xor(qv, m, 64);
    float rstd = rsqrtf(qv * 0.00390625f + 1e-5f);
    const float4 gg = *(const float4*)&gw[lane * 4];
    const float4 bb = *(const float4*)&bw[lane * 4];
    uint2 u;
    u.x = f2bf(d0 * rstd * gg.x + bb.x) | ((unsigned)f2bf(d1 * rstd * gg.y + bb.y) << 16);
    u.y = f2bf(d2 * rstd * gg.z + bb.z) | ((unsigned)f2bf(d3 * rstd * gg.w + bb.w) << 16);
    *(uint2*)&out[(size_t)row * 256 + lane * 4] = u;
}

// ---------------- fused attention v6 ----------------
// 1-D grid 1024: head = bid&7 -> all blocks of head h land on XCD h
// (round-robin dispatch), so each XCD's L2 holds ONE head's K/V (512KB,
// resident) + 1MB head-sliced Q stream. 256 thr = 4 waves; 32 queries/wave.
// Zero LDS/barriers; register P (k-axis permutation invariance); V stored
// key-permuted; ones-row MFMA denominator; 2-deep register prefetch pinned
// with sched_barrier(0) so the scheduler can't sink the loads (r5/r8 lesson).
__global__ __launch_bounds__(256, 4) void attn_kernel(
    const bf16* __restrict__ qh, const bf16* __restrict__ kh,
    const bf16* __restrict__ vt, bf16* __restrict__ obf)
{
    const int bid = blockIdx.x;
    const int h = bid & 7;                      // XCD-pinned head
    const int tile = bid >> 3;
    const int row0 = tile << 7;                 // 128 queries per block
    const int b = (row0 < 2048) ? 0 : (row0 < 8192) ? 1 : (row0 < 11264) ? 2 : 3;
    const int tid = threadIdx.x, lane = tid & 63, w = tid >> 6;
    const int l15 = lane & 15, g = lane >> 4;
    const int qbase = row0 + (w << 5);          // 32 queries per wave
    const int bh = (b << 3) + h;

    bf16x8 qfA = *(const bf16x8*)&qh[(size_t)(qbase + l15) * 256 + h * 32 + g * 8];
    bf16x8 qfB = *(const bf16x8*)&qh[(size_t)(qbase + 16 + l15) * 256 + h * 32 + g * 8];

    bf16x8 ones;
    {
        unsigned ov = (l15 == 0) ? 0x3f803f80u : 0u;
        unsigned* op = (unsigned*)&ones;
        op[0] = ov; op[1] = ov; op[2] = ov; op[3] = ov;
    }

    f32x4 o0A = {0.f,0.f,0.f,0.f}, o1A = o0A, o2A = o0A;
    f32x4 o0B = o0A, o1B = o0A, o2B = o0A;
    const f32x4 z = {0.f, 0.f, 0.f, 0.f};

    const bf16* kp  = kh + ((size_t)bh * 1024 + l15) * 32 + g * 8;
    const bf16* vp0 = vt + ((size_t)bh * 32 + l15) * 1024 + (g << 3);  // d = l15
    const bf16* vp1 = vp0 + 16 * 1024;                                  // d = 16+l15

    bf16x8 cK0 = *(const bf16x8*)(kp);
    bf16x8 cK1 = *(const bf16x8*)(kp + 512);
    bf16x8 cV0 = *(const bf16x8*)(vp0);
    bf16x8 cV1 = *(const bf16x8*)(vp1);
    bf16x8 nK0 = *(const bf16x8*)(kp + 1024);
    bf16x8 nK1 = *(const bf16x8*)(kp + 1536);
    bf16x8 nV0 = *(const bf16x8*)(vp0 + 32);
    bf16x8 nV1 = *(const bf16x8*)(vp1 + 32);

#pragma unroll 2
    for (int it = 0; it < 32; ++it) {
        // stage iteration it+2 (wraparound reload at the tail, discarded)
        const int fk = ((it + 2) & 31) << 5;
        bf16x8 fK0 = *(const bf16x8*)(kp + (size_t)fk * 32);
        bf16x8 fK1 = *(const bf16x8*)(kp + (size_t)fk * 32 + 512);
        bf16x8 fV0 = *(const bf16x8*)(vp0 + fk);
        bf16x8 fV1 = *(const bf16x8*)(vp1 + fk);
        // pin: prefetch loads may not sink below this point (r5/r8 failure mode)
        __builtin_amdgcn_sched_barrier(0);

        f32x4 s0A = mfma16(cK0, qfA, z);
        f32x4 s1A = mfma16(cK1, qfA, z);
        f32x4 s0B = mfma16(cK0, qfB, z);
        f32x4 s1B = mfma16(cK1, qfB, z);

        uint4 pAu, pBu;
        pAu.x = pk_rtz(ex2(s0A[0]), ex2(s0A[1]));
        pAu.y = pk_rtz(ex2(s0A[2]), ex2(s0A[3]));
        pAu.z = pk_rtz(ex2(s1A[0]), ex2(s1A[1]));
        pAu.w = pk_rtz(ex2(s1A[2]), ex2(s1A[3]));
        pBu.x = pk_rtz(ex2(s0B[0]), ex2(s0B[1]));
        pBu.y = pk_rtz(ex2(s0B[2]), ex2(s0B[3]));
        pBu.z = pk_rtz(ex2(s1B[0]), ex2(s1B[1]));
        pBu.w = pk_rtz(ex2(s1B[2]), ex2(s1B[3]));
        union { uint4 u; bf16x8 v; } cA, cB;
        cA.u = pAu; cB.u = pBu;

        o0A = mfma16(cA.v, cV0, o0A);
        o1A = mfma16(cA.v, cV1, o1A);
        o2A = mfma16(cA.v, ones, o2A);
        o0B = mfma16(cB.v, cV0, o0B);
        o1B = mfma16(cB.v, cV1, o1B);
        o2B = mfma16(cB.v, ones, o2B);

        cK0 = nK0; cK1 = nK1; cV0 = nV0; cV1 = nV1;
        nK0 = fK0; nK1 = fK1; nV0 = fV0; nV1 = fV1;
    }

#pragma unroll
    for (int r = 0; r < 4; ++r) {
        float invA = 1.f / __shfl(o2A[r], g << 4, 64);   // denom(q=4g+r) at lane 16g
        float invB = 1.f / __shfl(o2B[r], g << 4, 64);
        size_t orowA = (size_t)(qbase + (g << 2) + r) * 256 + h * 32;
        size_t orowB = (size_t)(qbase + 16 + (g << 2) + r) * 256 + h * 32;
        obf[orowA + l15]      = __float2bfloat16(o0A[r] * invA);
        obf[orowA + 16 + l15] = __float2bfloat16(o1A[r] * invA);
        obf[orowB + l15]      = __float2bfloat16(o0B[r] * invB);
        obf[orowB + 16 + l15] = __float2bfloat16(o1B[r] * invB);
    }
}

// ---------------- launcher ----------------

extern "C" void kernel_launch(void* const* d_in, const int* in_sizes, int n_in,
                              void* d_out, int out_size, void* d_ws, size_t ws_size,
                              hipStream_t stream)
{
    const float* x      = (const float*)d_in[0];
    const float* q      = (const float*)d_in[1];
    const float* w_q    = (const float*)d_in[5];
    const float* w_kv   = (const float*)d_in[6];
    const float* sr_w   = (const float*)d_in[7];
    const float* sr_b   = (const float*)d_in[8];
    const float* ln_g   = (const float*)d_in[9];
    const float* ln_b   = (const float*)d_in[10];
    const float* proj_w = (const float*)d_in[11];
    const float* proj_b = (const float*)d_in[12];

    char* w = (char*)d_ws;
    bf16* xim  = (bf16*)(w + 0);           // 33,554,432  (im2col bf16 [4096][4096])
    bf16* q_bf = (bf16*)(w + 33554432);    //  8,388,608
    bf16* qh   = (bf16*)(w + 41943040);    //  8,388,608
    bf16* wqT  = (bf16*)(w + 50331648);    //    131,072
    bf16* wkvT = (bf16*)(w + 50462720);    //    262,144
    bf16* wprT = (bf16*)(w + 50724864);    //    131,072
    bf16* wcv  = (bf16*)(w + 50855936);    //  2,097,152
    bf16* xln  = (bf16*)(w + 52953088);    //  2,097,152
    bf16* kh   = (bf16*)(w + 55050240);    //  2,097,152  (per-head K [bh][key][32])
    bf16* vt   = (bf16*)(w + 57147392);    //  2,097,152  (per-head V^T, key-permuted)
    bf16* obf  = (bf16*)(w + 59244544);    //  8,388,608 -> total 67,633,152
    // split-K partials [4][4096][256] f32 = 16 MB live in d_out (overwritten by out proj)
    float* partials = (float*)d_out;
    float* out = (float*)d_out;

    transpose_cast_kernel<<<256, 256, 0, stream>>>(w_q, wqT, 256, 256);
    transpose_cast_kernel<<<512, 256, 0, stream>>>(w_kv, wkvT, 256, 512);
    transpose_cast_kernel<<<256, 256, 0, stream>>>(proj_w, wprT, 256, 256);
    conv_w_kernel<<<4096, 256, 0, stream>>>(sr_w, wcv);
    cast_bf16_kernel<<<2048, 256, 0, stream>>>(q, q_bf, 524288);
    im2col_kernel<<<8192, 256, 0, stream>>>(x, xim);

    // q proj -> qh (pre-scaled by SCALE*log2e)
    gemm_kernel<0><<<1024, 256, 0, stream>>>(q_bf, wqT, nullptr, qh, nullptr, nullptr,
                                             16384, 256, 256, 256);
    // conv as GEMM on xim, split-K=4 -> partials in d_out
    gemm_kernel<3><<<dim3(256, 4), 256, 0, stream>>>(xim, wcv, nullptr, nullptr, partials,
                                                     nullptr, 4096, 256, 4096, 1024);
    // fused reduce(4 slices) + conv bias + LayerNorm -> xln bf16
    ln_kernel<<<1024, 256, 0, stream>>>(partials, sr_b, ln_g, ln_b, xln);
    // kv proj -> kh per-head [bh][key][32] and vt (key-permuted) [(b*8+h)*32+d][keyp]
    gemm_kernel<2><<<512, 256, 0, stream>>>(xln, wkvT, nullptr, kh, nullptr, vt,
                                            4096, 512, 256, 256);
    attn_kernel<<<1024, 256, 0, stream>>>(qh, kh, vt, obf);
    // out proj -> d_out (f32, +bias)
    gemm_kernel<1><<<1024, 256, 0, stream>>>(obf, wprT, proj_b, nullptr, out, nullptr,
                                             16384, 256, 256, 256);
}

// Round 10
// 109.643 us; speedup vs baseline: 1.2072x; 1.2072x over previous
//
#include <hip/hip_runtime.h>
#include <hip/hip_bf16.h>

// Pipeline: weight prep -> q cast + im2col cast of x -> qproj GEMM ->
//           conv-as-GEMM (A=xim bf16, split-K=4, partials in d_out) ->
//           fused reduce+bias+LN -> kvproj GEMM -> fused attention -> out proj.
// GEMM v3: T3-min 2-phase pipeline with __builtin_amdgcn_global_load_lds.
// Attention v7: K/V staged through double-buffered LDS with the SAME proven
//   2-phase gl16 structure (DMA state in vmcnt -> immune to regalloc sinking,
//   the r5/r8/r9 register-ring failure mode). 128-key windows, both-sides
//   XOR swizzle, 4 waves share one (b,h), head->XCD pinning kept.
// Workspace requirement: ~68 MB.

using bf16 = __hip_bfloat16;
using f32x4 = __attribute__((ext_vector_type(4))) float;
using bf16x8 = __attribute__((ext_vector_type(8))) short;

#define DEVINL __device__ __forceinline__
#define AS1 __attribute__((address_space(1)))
#define AS3 __attribute__((address_space(3)))

DEVINL f32x4 mfma16(bf16x8 a, bf16x8 b, f32x4 c) {
    return __builtin_amdgcn_mfma_f32_16x16x32_bf16(a, b, c, 0, 0, 0);
}

DEVINL unsigned short f2bf(float f) {
    union { float f; unsigned u; } x; x.f = f;
    unsigned u = x.u;
    u += 0x7fffu + ((u >> 16) & 1u);   // RNE
    return (unsigned short)(u >> 16);
}

// pack two f32 -> two bf16 (RTZ) in one v_perm: low16 = trunc(a), high16 = trunc(b)
DEVINL unsigned pk_rtz(float a, float b) {
    return __builtin_amdgcn_perm(__float_as_uint(b), __float_as_uint(a), 0x07060302u);
}

DEVINL float ex2(float x) { return __builtin_amdgcn_exp2f(x); }   // raw v_exp_f32

// async global->LDS DMA, 16B per lane. lds dest must be wave-uniform base
// (HW deposits at base + lane*16); global source is per-lane.
DEVINL void gl16(const bf16* g, bf16* l) {
    __builtin_amdgcn_global_load_lds(
        (const AS1 void*)(unsigned long long)(uintptr_t)g,
        (AS3 void*)(unsigned)(uintptr_t)l,
        16, 0, 0);
}

// ---------------- prep kernels ----------------

// f32 -> bf16, 8 elems/thread
__global__ __launch_bounds__(256) void cast_bf16_kernel(const float* __restrict__ in,
                                                        bf16* __restrict__ out, int n8) {
    int i = blockIdx.x * 256 + threadIdx.x;
    if (i >= n8) return;
    float4 a = ((const float4*)in)[i * 2];
    float4 b = ((const float4*)in)[i * 2 + 1];
    uint4 u;
    u.x = f2bf(a.x) | ((unsigned)f2bf(a.y) << 16);
    u.y = f2bf(a.z) | ((unsigned)f2bf(a.w) << 16);
    u.z = f2bf(b.x) | ((unsigned)f2bf(b.y) << 16);
    u.w = f2bf(b.z) | ((unsigned)f2bf(b.w) << 16);
    ((uint4*)out)[i] = u;
}

// im2col + cast: xim[pr][dydx*256+c] = x[b][(ii*4+dy)*128 + jj*4+dx][c]  (bf16)
__global__ __launch_bounds__(256) void im2col_kernel(const float* __restrict__ x,
                                                     bf16* __restrict__ xim) {
    int m = blockIdx.x * 256 + threadIdx.x;    // chunk id: pr*512 + dydx*32 + cchunk
    int cc8 = (m & 31) << 3;
    int dydx = (m >> 5) & 15;
    int pr = m >> 9;
    int b = pr >> 10, pi = pr & 1023;
    int ii = pi >> 5, jj = pi & 31;
    int dy = dydx >> 2, dx = dydx & 3;
    int pos = ((ii << 2) + dy) * 128 + (jj << 2) + dx;
    const float* s = &x[(size_t)((b << 14) + pos) * 256 + cc8];
    float4 a = *(const float4*)s;
    float4 c = *(const float4*)(s + 4);
    uint4 u;
    u.x = f2bf(a.x) | ((unsigned)f2bf(a.y) << 16);
    u.y = f2bf(a.z) | ((unsigned)f2bf(a.w) << 16);
    u.z = f2bf(c.x) | ((unsigned)f2bf(c.y) << 16);
    u.w = f2bf(c.z) | ((unsigned)f2bf(c.w) << 16);
    *(uint4*)&xim[(size_t)m * 8] = u;
}

// out[n*K + k] = in[k*N + n]  (weight [K,N] -> [N,K] bf16)
__global__ __launch_bounds__(256) void transpose_cast_kernel(const float* __restrict__ in,
                                                             bf16* __restrict__ out, int K, int N) {
    int idx = blockIdx.x * 256 + threadIdx.x;
    if (idx >= K * N) return;
    int k = idx % K, n = idx / K;
    out[idx] = __float2bfloat16(in[k * N + n]);
}

// wcv[o*4096 + dydx*256 + c] = sr_w[o][c][dy][dx]   (OIHW, 4x4)
__global__ __launch_bounds__(256) void conv_w_kernel(const float* __restrict__ sr_w,
                                                     bf16* __restrict__ out) {
    int idx = blockIdx.x * 256 + threadIdx.x;   // exact grid: 4096*256 = 1048576
    int o = idx >> 12, rest = idx & 4095, dydx = rest >> 8, c = rest & 255;
    out[idx] = __float2bfloat16(sr_w[((o << 8) + c) * 16 + dydx]);
}

// ---------------- GEMM (all-bf16, global_load_lds 2-phase) ----------------
template<int EMODE>
__global__ __launch_bounds__(256, 4) void gemm_kernel(
    const bf16* __restrict__ A, const bf16* __restrict__ WT,
    const float* __restrict__ bias,
    bf16* __restrict__ outb, float* __restrict__ outf, bf16* __restrict__ out2,
    int M, int N, int K, int KS)
{
    __shared__ alignas(16) bf16 As[2][64 * 64];
    __shared__ alignas(16) bf16 Bs[2][64 * 64];
    // XCD-chunked swizzle: XCD (bx%8) gets a contiguous tm-range with all tn.
    const int cpx = gridDim.x >> 3;
    const int bx = (blockIdx.x & 7) * cpx + (blockIdx.x >> 3);
    const int ntn = N >> 6;
    const int tm = bx / ntn, tn = bx % ntn;
    const int tid = threadIdx.x, lane = tid & 63, wid = tid >> 6;
    const int l15 = lane & 15, g = lane >> 4;
    const int wm = (wid >> 1) << 5, wn = (wid & 1) << 5;
    f32x4 acc[2][2] = {};

    int r_[2], cs_[2];
#pragma unroll
    for (int j = 0; j < 2; ++j) {
        int idx = (wid * 2 + j) * 64 + lane;
        r_[j] = idx >> 3;
        cs_[j] = ((idx & 7) ^ (r_[j] & 7)) << 3;   // pre-swizzled source column
    }
    const bf16* Arow = &A[(size_t)(tm * 64) * K];
    const bf16* Brow = &WT[(size_t)(tn * 64) * K];

    const int kbeg = blockIdx.y * KS;
    const int nsteps = KS >> 6;

    auto stage = [&](int buf, int k0) {
#pragma unroll
        for (int j = 0; j < 2; ++j) {
            gl16(Arow + (size_t)r_[j] * K + (k0 + cs_[j]), &As[buf][(wid * 2 + j) * 512]);
            gl16(Brow + (size_t)r_[j] * K + (k0 + cs_[j]), &Bs[buf][(wid * 2 + j) * 512]);
        }
    };

    stage(0, kbeg);
    __syncthreads();                     // vmcnt(0) drain + barrier

    for (int t = 0; t < nsteps; ++t) {
        const int buf = t & 1;
        if (t + 1 < nsteps) stage(buf ^ 1, kbeg + (t + 1) * 64);  // in flight across compute
#pragma unroll
        for (int kk = 0; kk < 2; ++kk) {
            const int sw = l15 & 7;
            const int co = ((kk * 4 + g) ^ sw) << 3;
            bf16x8 a0 = *(const bf16x8*)&As[buf][(wm + l15) * 64 + co];
            bf16x8 a1 = *(const bf16x8*)&As[buf][(wm + 16 + l15) * 64 + co];
            bf16x8 b0 = *(const bf16x8*)&Bs[buf][(wn + l15) * 64 + co];
            bf16x8 b1 = *(const bf16x8*)&Bs[buf][(wn + 16 + l15) * 64 + co];
            acc[0][0] = mfma16(a0, b0, acc[0][0]);
            acc[0][1] = mfma16(a0, b1, acc[0][1]);
            acc[1][0] = mfma16(a1, b0, acc[1][0]);
            acc[1][1] = mfma16(a1, b1, acc[1][1]);
        }
        __syncthreads();
    }

    const float qscale = 0.1767766953f * 1.4426950409f;  // HD^-0.5 * log2(e)
#pragma unroll
    for (int mi = 0; mi < 2; ++mi)
#pragma unroll
    for (int ni = 0; ni < 2; ++ni)
#pragma unroll
    for (int r = 0; r < 4; ++r) {
        int row = tm * 64 + wm + mi * 16 + g * 4 + r;
        int col = tn * 64 + wn + ni * 16 + l15;
        float v = acc[mi][ni][r];
        if constexpr (EMODE == 0) {
            outb[(size_t)row * 256 + col] = __float2bfloat16(v * qscale);
        } else if constexpr (EMODE == 1) {
            outf[(size_t)row * 256 + col] = v + bias[col];
        } else if constexpr (EMODE == 2) {
            int bb = row >> 10, key = row & 1023;
            if (col < 256) {
                int hh = col >> 5, d = col & 31;
                outb[(size_t)(((bb << 3) + hh) * 1024 + key) * 32 + d] = __float2bfloat16(v);
            } else {
                int d = col - 256;
                // key-permuted position within its 32-block: PV B-fragment order
                int c = key & 31;
                int pos = (((c >> 2) & 3) << 3) + ((c >> 4) << 2) + (c & 3);
                int keyp = (key & ~31) | pos;
                out2[(size_t)(((bb << 3) + (d >> 5)) * 32 + (d & 31)) * 1024 + keyp] =
                    __float2bfloat16(v);
            }
        } else {
            outf[((size_t)blockIdx.y * 4096 + row) * 256 + col] = v;
        }
    }
}

// ------- fused split-K reduce + conv bias + LayerNorm (C=256, one wave/row) -------
__global__ __launch_bounds__(256) void ln_kernel(const float* __restrict__ pp,
                                                 const float* __restrict__ cb,
                                                 const float* __restrict__ gw,
                                                 const float* __restrict__ bw,
                                                 bf16* __restrict__ out) {
    int row = blockIdx.x * 4 + (threadIdx.x >> 6);
    int lane = threadIdx.x & 63;
    const size_t base = (size_t)row * 256 + lane * 4;
    float4 v = *(const float4*)&pp[base];
#pragma unroll
    for (int s = 1; s < 4; ++s) {
        const float4 t = *(const float4*)&pp[(size_t)s * (4096 * 256) + base];
        v.x += t.x; v.y += t.y; v.z += t.z; v.w += t.w;
    }
    const float4 cbv = *(const float4*)&cb[lane * 4];
    v.x += cbv.x; v.y += cbv.y; v.z += cbv.z; v.w += cbv.w;

    float s = v.x + v.y + v.z + v.w;
#pragma unroll
    for (int m = 1; m < 64; m <<= 1) s += __shfl_xor(s, m, 64);
    float mu = s * 0.00390625f;
    float d0 = v.x - mu, d1 = v.y - mu, d2 = v.z - mu, d3 = v.w - mu;
    float qv = d0 * d0 + d1 * d1 + d2 * d2 + d3 * d3;
#pragma unroll
    for (int m = 1; m < 64; m <<= 1) qv += __shfl_xor(qv, m, 64);
    float rstd = rsqrtf(qv * 0.00390625f + 1e-5f);
    const float4 gg = *(const float4*)&gw[lane * 4];
    const float4 bb = *(const float4*)&bw[lane * 4];
    uint2 u;
    u.x = f2bf(d0 * rstd * gg.x + bb.x) | ((unsigned)f2bf(d1 * rstd * gg.y + bb.y) << 16);
    u.y = f2bf(d2 * rstd * gg.z + bb.z) | ((unsigned)f2bf(d3 * rstd * gg.w + bb.w) << 16);
    *(uint2*)&out[(size_t)row * 256 + lane * 4] = u;
}

// ---------------- fused attention v7 (LDS-staged K/V, 2-phase gl16) ----------------
// 1-D grid 1024: head = bid&7 (XCD-pinned). 256 thr = 4 waves sharing one
// (b,h); each wave owns 32 queries. K/V staged in double-buffered LDS via
// global_load_lds in 128-key windows (waves 0-1 stage K, 2-3 stage V; 4 calls
// each); one __syncthreads per window = vmcnt(0) drain (the r8-proven GEMM
// skeleton -- DMA state lives in vmcnt, regalloc can't sink it).
// Both-sides XOR swizzle (rule #21): K chunk ^= key&3, V chunk ^= d&7,
// applied on the GLOBAL source (LDS dest linear) and re-applied on ds_read.
// Math unchanged: swapped QK^T, register P (k-permutation invariance),
// key-permuted V, ones-row MFMA denominator, raw v_exp_f32.
__global__ __launch_bounds__(256, 4) void attn_kernel(
    const bf16* __restrict__ qh, const bf16* __restrict__ kh,
    const bf16* __restrict__ vt, bf16* __restrict__ obf)
{
    __shared__ alignas(16) bf16 Kl[2][128 * 32];   // [key][chunk g^(key&3)][8]
    __shared__ alignas(16) bf16 Vl[2][32 * 128];   // [d][chunk c^(d&7)][8]
    const int bid = blockIdx.x;
    const int h = bid & 7;                      // XCD-pinned head
    const int tile = bid >> 3;
    const int row0 = tile << 7;                 // 128 queries per block
    const int b = (row0 < 2048) ? 0 : (row0 < 8192) ? 1 : (row0 < 11264) ? 2 : 3;
    const int tid = threadIdx.x, lane = tid & 63, w = tid >> 6;
    const int l15 = lane & 15, g = lane >> 4;
    const int qbase = row0 + (w << 5);          // 32 queries per wave
    const int bh = (b << 3) + h;

    bf16x8 qfA = *(const bf16x8*)&qh[(size_t)(qbase + l15) * 256 + h * 32 + g * 8];
    bf16x8 qfB = *(const bf16x8*)&qh[(size_t)(qbase + 16 + l15) * 256 + h * 32 + g * 8];

    bf16x8 ones;
    {
        unsigned ov = (l15 == 0) ? 0x3f803f80u : 0u;
        unsigned* op = (unsigned*)&ones;
        op[0] = ov; op[1] = ov; op[2] = ov; op[3] = ov;
    }

    f32x4 o0A = {0.f,0.f,0.f,0.f}, o1A = o0A, o2A = o0A;
    f32x4 o0B = o0A, o1B = o0A, o2B = o0A;
    const f32x4 z = {0.f, 0.f, 0.f, 0.f};

    // staging source coords (per lane, fixed across windows)
    const int skey = lane >> 2;                         // K: key within 16-row group
    const int skc  = (lane & 3) ^ (skey & 3);           //    pre-swizzled chunk
    const int svd  = lane >> 4;                         // V: d within 4-row group
    const int svc  = lane & 15;                         //    chunk (swizzle added per call)
    const bf16* kbase = kh + (size_t)bh * 1024 * 32;
    const bf16* vbase = vt + (size_t)bh * 32 * 1024;

    auto stage = [&](int buf, int kb) {
        if (w < 2) {
#pragma unroll
            for (int jj = 0; jj < 4; ++jj) {
                int j = w * 4 + jj;                     // 16-key group 0..7
                int key = (j << 4) + skey;
                gl16(kbase + (size_t)(kb + key) * 32 + (skc << 3), &Kl[buf][j * 512]);
            }
        } else {
#pragma unroll
            for (int jj = 0; jj < 4; ++jj) {
                int j = (w - 2) * 4 + jj;               // 4-d group 0..7
                int d = (j << 2) + svd;
                gl16(vbase + (size_t)d * 1024 + kb + ((svc ^ (d & 7)) << 3),
                     &Vl[buf][j * 512]);
            }
        }
    };

    stage(0, 0);
    __syncthreads();                     // vmcnt(0) drain + barrier

    const int kc = g ^ (l15 & 3);        // K read chunk (swizzled)
    const int vsw = l15 & 7;             // V read swizzle

    for (int t = 0; t < 8; ++t) {
        const int buf = t & 1;
        if (t < 7) stage(buf ^ 1, (t + 1) << 7);   // next window in flight
#pragma unroll
        for (int s = 0; s < 4; ++s) {
            bf16x8 k0 = *(const bf16x8*)&Kl[buf][((s << 5) + l15) * 32 + (kc << 3)];
            bf16x8 k1 = *(const bf16x8*)&Kl[buf][((s << 5) + 16 + l15) * 32 + (kc << 3)];
            bf16x8 v0 = *(const bf16x8*)&Vl[buf][(l15 << 7) + ((((s << 2) + g) ^ vsw) << 3)];
            bf16x8 v1 = *(const bf16x8*)&Vl[buf][((16 + l15) << 7) + ((((s << 2) + g) ^ vsw) << 3)];

            f32x4 s0A = mfma16(k0, qfA, z);
            f32x4 s1A = mfma16(k1, qfA, z);
            f32x4 s0B = mfma16(k0, qfB, z);
            f32x4 s1B = mfma16(k1, qfB, z);

            uint4 pAu, pBu;
            pAu.x = pk_rtz(ex2(s0A[0]), ex2(s0A[1]));
            pAu.y = pk_rtz(ex2(s0A[2]), ex2(s0A[3]));
            pAu.z = pk_rtz(ex2(s1A[0]), ex2(s1A[1]));
            pAu.w = pk_rtz(ex2(s1A[2]), ex2(s1A[3]));
            pBu.x = pk_rtz(ex2(s0B[0]), ex2(s0B[1]));
            pBu.y = pk_rtz(ex2(s0B[2]), ex2(s0B[3]));
            pBu.z = pk_rtz(ex2(s1B[0]), ex2(s1B[1]));
            pBu.w = pk_rtz(ex2(s1B[2]), ex2(s1B[3]));
            union { uint4 u; bf16x8 v; } cA, cB;
            cA.u = pAu; cB.u = pBu;

            o0A = mfma16(cA.v, v0, o0A);
            o1A = mfma16(cA.v, v1, o1A);
            o2A = mfma16(cA.v, ones, o2A);
            o0B = mfma16(cB.v, v0, o0B);
            o1B = mfma16(cB.v, v1, o1B);
            o2B = mfma16(cB.v, ones, o2B);
        }
        __syncthreads();                 // next window landed; buf reads done
    }

#pragma unroll
    for (int r = 0; r < 4; ++r) {
        float invA = 1.f / __shfl(o2A[r], g << 4, 64);   // denom(q=4g+r) at lane 16g
        float invB = 1.f / __shfl(o2B[r], g << 4, 64);
        size_t orowA = (size_t)(qbase + (g << 2) + r) * 256 + h * 32;
        size_t orowB = (size_t)(qbase + 16 + (g << 2) + r) * 256 + h * 32;
        obf[orowA + l15]      = __float2bfloat16(o0A[r] * invA);
        obf[orowA + 16 + l15] = __float2bfloat16(o1A[r] * invA);
        obf[orowB + l15]      = __float2bfloat16(o0B[r] * invB);
        obf[orowB + 16 + l15] = __float2bfloat16(o1B[r] * invB);
    }
}

// ---------------- launcher ----------------

extern "C" void kernel_launch(void* const* d_in, const int* in_sizes, int n_in,
                              void* d_out, int out_size, void* d_ws, size_t ws_size,
                              hipStream_t stream)
{
    const float* x      = (const float*)d_in[0];
    const float* q      = (const float*)d_in[1];
    const float* w_q    = (const float*)d_in[5];
    const float* w_kv   = (const float*)d_in[6];
    const float* sr_w   = (const float*)d_in[7];
    const float* sr_b   = (const float*)d_in[8];
    const float* ln_g   = (const float*)d_in[9];
    const float* ln_b   = (const float*)d_in[10];
    const float* proj_w = (const float*)d_in[11];
    const float* proj_b = (const float*)d_in[12];

    char* w = (char*)d_ws;
    bf16* xim  = (bf16*)(w + 0);           // 33,554,432  (im2col bf16 [4096][4096])
    bf16* q_bf = (bf16*)(w + 33554432);    //  8,388,608
    bf16* qh   = (bf16*)(w + 41943040);    //  8,388,608
    bf16* wqT  = (bf16*)(w + 50331648);    //    131,072
    bf16* wkvT = (bf16*)(w + 50462720);    //    262,144
    bf16* wprT = (bf16*)(w + 50724864);    //    131,072
    bf16* wcv  = (bf16*)(w + 50855936);    //  2,097,152
    bf16* xln  = (bf16*)(w + 52953088);    //  2,097,152
    bf16* kh   = (bf16*)(w + 55050240);    //  2,097,152  (per-head K [bh][key][32])
    bf16* vt   = (bf16*)(w + 57147392);    //  2,097,152  (per-head V^T, key-permuted)
    bf16* obf  = (bf16*)(w + 59244544);    //  8,388,608 -> total 67,633,152
    // split-K partials [4][4096][256] f32 = 16 MB live in d_out (overwritten by out proj)
    float* partials = (float*)d_out;
    float* out = (float*)d_out;

    transpose_cast_kernel<<<256, 256, 0, stream>>>(w_q, wqT, 256, 256);
    transpose_cast_kernel<<<512, 256, 0, stream>>>(w_kv, wkvT, 256, 512);
    transpose_cast_kernel<<<256, 256, 0, stream>>>(proj_w, wprT, 256, 256);
    conv_w_kernel<<<4096, 256, 0, stream>>>(sr_w, wcv);
    cast_bf16_kernel<<<2048, 256, 0, stream>>>(q, q_bf, 524288);
    im2col_kernel<<<8192, 256, 0, stream>>>(x, xim);

    // q proj -> qh (pre-scaled by SCALE*log2e)
    gemm_kernel<0><<<1024, 256, 0, stream>>>(q_bf, wqT, nullptr, qh, nullptr, nullptr,
                                             16384, 256, 256, 256);
    // conv as GEMM on xim, split-K=4 -> partials in d_out
    gemm_kernel<3><<<dim3(256, 4), 256, 0, stream>>>(xim, wcv, nullptr, nullptr, partials,
                                                     nullptr, 4096, 256, 4096, 1024);
    // fused reduce(4 slices) + conv bias + LayerNorm -> xln bf16
    ln_kernel<<<1024, 256, 0, stream>>>(partials, sr_b, ln_g, ln_b, xln);
    // kv proj -> kh per-head [bh][key][32] and vt (key-permuted) [(b*8+h)*32+d][keyp]
    gemm_kernel<2><<<512, 256, 0, stream>>>(xln, wkvT, nullptr, kh, nullptr, vt,
                                            4096, 512, 256, 256);
    attn_kernel<<<1024, 256, 0, stream>>>(qh, kh, vt, obf);
    // out proj -> d_out (f32, +bias)
    gemm_kernel<1><<<1024, 256, 0, stream>>>(obf, wprT, proj_b, nullptr, out, nullptr,
                                             16384, 256, 256, 256);
}

// Round 11
// 109.523 us; speedup vs baseline: 1.2085x; 1.0011x over previous
//
#include <hip/hip_runtime.h>
#include <hip/hip_bf16.h>

// Pipeline: weight prep -> q cast + im2col cast of x -> qproj GEMM ->
//           conv-as-GEMM (IN-BLOCK split-K=4, 1024 thr, partials reduced in
//           LDS, final f32+bias written once) -> LN -> kvproj GEMM ->
//           fused attention (LDS-staged, r10) -> out proj GEMM.
// All GEMMs + attention use the proven 2-phase __builtin_amdgcn_global_load_lds
// skeleton (DMA state in vmcnt -> immune to regalloc sinking).
// Workspace requirement: ~72 MB.

using bf16 = __hip_bfloat16;
using f32x4 = __attribute__((ext_vector_type(4))) float;
using bf16x8 = __attribute__((ext_vector_type(8))) short;

#define DEVINL __device__ __forceinline__
#define AS1 __attribute__((address_space(1)))
#define AS3 __attribute__((address_space(3)))

DEVINL f32x4 mfma16(bf16x8 a, bf16x8 b, f32x4 c) {
    return __builtin_amdgcn_mfma_f32_16x16x32_bf16(a, b, c, 0, 0, 0);
}

DEVINL unsigned short f2bf(float f) {
    union { float f; unsigned u; } x; x.f = f;
    unsigned u = x.u;
    u += 0x7fffu + ((u >> 16) & 1u);   // RNE
    return (unsigned short)(u >> 16);
}

// pack two f32 -> two bf16 (RTZ) in one v_perm: low16 = trunc(a), high16 = trunc(b)
DEVINL unsigned pk_rtz(float a, float b) {
    return __builtin_amdgcn_perm(__float_as_uint(b), __float_as_uint(a), 0x07060302u);
}

DEVINL float ex2(float x) { return __builtin_amdgcn_exp2f(x); }   // raw v_exp_f32

// async global->LDS DMA, 16B per lane. lds dest must be wave-uniform base
// (HW deposits at base + lane*16); global source is per-lane.
DEVINL void gl16(const bf16* g, bf16* l) {
    __builtin_amdgcn_global_load_lds(
        (const AS1 void*)(unsigned long long)(uintptr_t)g,
        (AS3 void*)(unsigned)(uintptr_t)l,
        16, 0, 0);
}

// ---------------- prep kernels ----------------

// f32 -> bf16, 8 elems/thread
__global__ __launch_bounds__(256) void cast_bf16_kernel(const float* __restrict__ in,
                                                        bf16* __restrict__ out, int n8) {
    int i = blockIdx.x * 256 + threadIdx.x;
    if (i >= n8) return;
    float4 a = ((const float4*)in)[i * 2];
    float4 b = ((const float4*)in)[i * 2 + 1];
    uint4 u;
    u.x = f2bf(a.x) | ((unsigned)f2bf(a.y) << 16);
    u.y = f2bf(a.z) | ((unsigned)f2bf(a.w) << 16);
    u.z = f2bf(b.x) | ((unsigned)f2bf(b.y) << 16);
    u.w = f2bf(b.z) | ((unsigned)f2bf(b.w) << 16);
    ((uint4*)out)[i] = u;
}

// im2col + cast: xim[pr][dydx*256+c] = x[b][(ii*4+dy)*128 + jj*4+dx][c]  (bf16)
__global__ __launch_bounds__(256) void im2col_kernel(const float* __restrict__ x,
                                                     bf16* __restrict__ xim) {
    int m = blockIdx.x * 256 + threadIdx.x;    // chunk id: pr*512 + dydx*32 + cchunk
    int cc8 = (m & 31) << 3;
    int dydx = (m >> 5) & 15;
    int pr = m >> 9;
    int b = pr >> 10, pi = pr & 1023;
    int ii = pi >> 5, jj = pi & 31;
    int dy = dydx >> 2, dx = dydx & 3;
    int pos = ((ii << 2) + dy) * 128 + (jj << 2) + dx;
    const float* s = &x[(size_t)((b << 14) + pos) * 256 + cc8];
    float4 a = *(const float4*)s;
    float4 c = *(const float4*)(s + 4);
    uint4 u;
    u.x = f2bf(a.x) | ((unsigned)f2bf(a.y) << 16);
    u.y = f2bf(a.z) | ((unsigned)f2bf(a.w) << 16);
    u.z = f2bf(c.x) | ((unsigned)f2bf(c.y) << 16);
    u.w = f2bf(c.z) | ((unsigned)f2bf(c.w) << 16);
    *(uint4*)&xim[(size_t)m * 8] = u;
}

// out[n*K + k] = in[k*N + n]  (weight [K,N] -> [N,K] bf16)
__global__ __launch_bounds__(256) void transpose_cast_kernel(const float* __restrict__ in,
                                                             bf16* __restrict__ out, int K, int N) {
    int idx = blockIdx.x * 256 + threadIdx.x;
    if (idx >= K * N) return;
    int k = idx % K, n = idx / K;
    out[idx] = __float2bfloat16(in[k * N + n]);
}

// wcv[o*4096 + dydx*256 + c] = sr_w[o][c][dy][dx]   (OIHW, 4x4)
__global__ __launch_bounds__(256) void conv_w_kernel(const float* __restrict__ sr_w,
                                                     bf16* __restrict__ out) {
    int idx = blockIdx.x * 256 + threadIdx.x;   // exact grid: 4096*256 = 1048576
    int o = idx >> 12, rest = idx & 4095, dydx = rest >> 8, c = rest & 255;
    out[idx] = __float2bfloat16(sr_w[((o << 8) + c) * 16 + dydx]);
}

// ---------------- GEMM (all-bf16, global_load_lds 2-phase) ----------------
template<int EMODE>
__global__ __launch_bounds__(256, 4) void gemm_kernel(
    const bf16* __restrict__ A, const bf16* __restrict__ WT,
    const float* __restrict__ bias,
    bf16* __restrict__ outb, float* __restrict__ outf, bf16* __restrict__ out2,
    int M, int N, int K, int KS)
{
    __shared__ alignas(16) bf16 As[2][64 * 64];
    __shared__ alignas(16) bf16 Bs[2][64 * 64];
    // XCD-chunked swizzle: XCD (bx%8) gets a contiguous tm-range with all tn.
    const int cpx = gridDim.x >> 3;
    const int bx = (blockIdx.x & 7) * cpx + (blockIdx.x >> 3);
    const int ntn = N >> 6;
    const int tm = bx / ntn, tn = bx % ntn;
    const int tid = threadIdx.x, lane = tid & 63, wid = tid >> 6;
    const int l15 = lane & 15, g = lane >> 4;
    const int wm = (wid >> 1) << 5, wn = (wid & 1) << 5;
    f32x4 acc[2][2] = {};

    int r_[2], cs_[2];
#pragma unroll
    for (int j = 0; j < 2; ++j) {
        int idx = (wid * 2 + j) * 64 + lane;
        r_[j] = idx >> 3;
        cs_[j] = ((idx & 7) ^ (r_[j] & 7)) << 3;   // pre-swizzled source column
    }
    const bf16* Arow = &A[(size_t)(tm * 64) * K];
    const bf16* Brow = &WT[(size_t)(tn * 64) * K];

    const int kbeg = blockIdx.y * KS;
    const int nsteps = KS >> 6;

    auto stage = [&](int buf, int k0) {
#pragma unroll
        for (int j = 0; j < 2; ++j) {
            gl16(Arow + (size_t)r_[j] * K + (k0 + cs_[j]), &As[buf][(wid * 2 + j) * 512]);
            gl16(Brow + (size_t)r_[j] * K + (k0 + cs_[j]), &Bs[buf][(wid * 2 + j) * 512]);
        }
    };

    stage(0, kbeg);
    __syncthreads();                     // vmcnt(0) drain + barrier

    for (int t = 0; t < nsteps; ++t) {
        const int buf = t & 1;
        if (t + 1 < nsteps) stage(buf ^ 1, kbeg + (t + 1) * 64);  // in flight across compute
#pragma unroll
        for (int kk = 0; kk < 2; ++kk) {
            const int sw = l15 & 7;
            const int co = ((kk * 4 + g) ^ sw) << 3;
            bf16x8 a0 = *(const bf16x8*)&As[buf][(wm + l15) * 64 + co];
            bf16x8 a1 = *(const bf16x8*)&As[buf][(wm + 16 + l15) * 64 + co];
            bf16x8 b0 = *(const bf16x8*)&Bs[buf][(wn + l15) * 64 + co];
            bf16x8 b1 = *(const bf16x8*)&Bs[buf][(wn + 16 + l15) * 64 + co];
            acc[0][0] = mfma16(a0, b0, acc[0][0]);
            acc[0][1] = mfma16(a0, b1, acc[0][1]);
            acc[1][0] = mfma16(a1, b0, acc[1][0]);
            acc[1][1] = mfma16(a1, b1, acc[1][1]);
        }
        __syncthreads();
    }

    const float qscale = 0.1767766953f * 1.4426950409f;  // HD^-0.5 * log2(e)
#pragma unroll
    for (int mi = 0; mi < 2; ++mi)
#pragma unroll
    for (int ni = 0; ni < 2; ++ni)
#pragma unroll
    for (int r = 0; r < 4; ++r) {
        int row = tm * 64 + wm + mi * 16 + g * 4 + r;
        int col = tn * 64 + wn + ni * 16 + l15;
        float v = acc[mi][ni][r];
        if constexpr (EMODE == 0) {
            outb[(size_t)row * 256 + col] = __float2bfloat16(v * qscale);
        } else if constexpr (EMODE == 1) {
            outf[(size_t)row * 256 + col] = v + bias[col];
        } else if constexpr (EMODE == 2) {
            int bb = row >> 10, key = row & 1023;
            if (col < 256) {
                int hh = col >> 5, d = col & 31;
                outb[(size_t)(((bb << 3) + hh) * 1024 + key) * 32 + d] = __float2bfloat16(v);
            } else {
                int d = col - 256;
                // key-permuted position within its 32-block: PV B-fragment order
                int c = key & 31;
                int pos = (((c >> 2) & 3) << 3) + ((c >> 4) << 2) + (c & 3);
                int keyp = (key & ~31) | pos;
                out2[(size_t)(((bb << 3) + (d >> 5)) * 32 + (d & 31)) * 1024 + keyp] =
                    __float2bfloat16(v);
            }
        }
    }
}

// ------- conv GEMM with IN-BLOCK split-K=4 (1024 thr = 4 wave-groups) -------
// C[4096,256] = xim[4096,4096] * wcv[256,4096]^T. 64x64 tile/block, grid 256.
// Wave-group grp (4 waves) runs the proven 2-phase gl16 loop on K-quarter
// [grp*1024, grp*1024+1024) into its own LDS quadrant (16 steps). Partials
// are then reduced through LDS (reusing As after the last barrier), bias
// added, final f32 written ONCE -- the 128 MB HBM partial round-trip of the
// cross-block split-K is eliminated.
__global__ __launch_bounds__(1024, 4) void conv_gemm_kernel(
    const bf16* __restrict__ A, const bf16* __restrict__ WT,
    const float* __restrict__ bias, float* __restrict__ outf)
{
    __shared__ alignas(16) bf16 As[4][2][64 * 64];   // 64 KB
    __shared__ alignas(16) bf16 Bs[4][2][64 * 64];   // 64 KB
    const int K = 4096;
    // XCD-chunked swizzle over 256 blocks (tm-major logical order)
    const int bx = (blockIdx.x & 7) * 32 + (blockIdx.x >> 3);
    const int tm = bx >> 2, tn = bx & 3;
    const int tid = threadIdx.x, lane = tid & 63, wid = tid >> 6;
    const int grp = wid >> 2, wg = wid & 3;          // K-group, wave within group
    const int l15 = lane & 15, g = lane >> 4;
    const int wm = (wg >> 1) << 5, wn = (wg & 1) << 5;
    f32x4 acc[2][2] = {};

    int r_[2], cs_[2];
#pragma unroll
    for (int j = 0; j < 2; ++j) {
        int idx = (wg * 2 + j) * 64 + lane;          // 0..511 within group
        r_[j] = idx >> 3;
        cs_[j] = ((idx & 7) ^ (r_[j] & 7)) << 3;     // pre-swizzled source column
    }
    const bf16* Arow = &A[(size_t)(tm * 64) * K];
    const bf16* Brow = &WT[(size_t)(tn * 64) * K];
    const int kbeg = grp << 10;                      // this group's K-quarter

    auto stage = [&](int buf, int k0) {
#pragma unroll
        for (int j = 0; j < 2; ++j) {
            gl16(Arow + (size_t)r_[j] * K + (k0 + cs_[j]), &As[grp][buf][(wg * 2 + j) * 512]);
            gl16(Brow + (size_t)r_[j] * K + (k0 + cs_[j]), &Bs[grp][buf][(wg * 2 + j) * 512]);
        }
    };

    stage(0, kbeg);
    __syncthreads();                     // vmcnt(0) drain + barrier

    for (int t = 0; t < 16; ++t) {
        const int buf = t & 1;
        if (t < 15) stage(buf ^ 1, kbeg + (t + 1) * 64);
#pragma unroll
        for (int kk = 0; kk < 2; ++kk) {
            const int sw = l15 & 7;
            const int co = ((kk * 4 + g) ^ sw) << 3;
            bf16x8 a0 = *(const bf16x8*)&As[grp][buf][(wm + l15) * 64 + co];
            bf16x8 a1 = *(const bf16x8*)&As[grp][buf][(wm + 16 + l15) * 64 + co];
            bf16x8 b0 = *(const bf16x8*)&Bs[grp][buf][(wn + l15) * 64 + co];
            bf16x8 b1 = *(const bf16x8*)&Bs[grp][buf][(wn + 16 + l15) * 64 + co];
            acc[0][0] = mfma16(a0, b0, acc[0][0]);
            acc[0][1] = mfma16(a0, b1, acc[0][1]);
            acc[1][0] = mfma16(a1, b0, acc[1][0]);
            acc[1][1] = mfma16(a1, b1, acc[1][1]);
        }
        __syncthreads();
    }

    // ---- in-LDS reduction across the 4 K-groups (reuse As as f32 scratch) ----
    float* red = (float*)&As[0][0][0];               // [4][64*64] f32 = 64 KB
#pragma unroll
    for (int mi = 0; mi < 2; ++mi)
#pragma unroll
    for (int ni = 0; ni < 2; ++ni)
#pragma unroll
    for (int r = 0; r < 4; ++r) {
        int row = wm + mi * 16 + g * 4 + r;
        int col = wn + ni * 16 + l15;
        red[(grp << 12) + row * 64 + col] = acc[mi][ni][r];
    }
    __syncthreads();

    // each thread reduces 4 consecutive elements (1024 thr x 4 = 4096)
    {
        const int e = tid << 2;
        float4 s = *(const float4*)&red[e];
        const float4 s1 = *(const float4*)&red[4096 + e];
        const float4 s2 = *(const float4*)&red[8192 + e];
        const float4 s3 = *(const float4*)&red[12288 + e];
        s.x += s1.x + s2.x + s3.x;
        s.y += s1.y + s2.y + s3.y;
        s.z += s1.z + s2.z + s3.z;
        s.w += s1.w + s2.w + s3.w;
        const int row = e >> 6, col = e & 63;
        const float4 bv = *(const float4*)&bias[tn * 64 + col];
        s.x += bv.x; s.y += bv.y; s.z += bv.z; s.w += bv.w;
        *(float4*)&outf[(size_t)(tm * 64 + row) * 256 + tn * 64 + col] = s;
    }
}

// ------- LayerNorm over C=256, one wave per row (bias already applied) -------
__global__ __launch_bounds__(256) void ln_kernel(const float* __restrict__ xr,
                                                 const float* __restrict__ gw,
                                                 const float* __restrict__ bw,
                                                 bf16* __restrict__ out) {
    int row = blockIdx.x * 4 + (threadIdx.x >> 6);
    int lane = threadIdx.x & 63;
    const float4 v = *(const float4*)&xr[(size_t)row * 256 + lane * 4];

    float s = v.x + v.y + v.z + v.w;
#pragma unroll
    for (int m = 1; m < 64; m <<= 1) s += __shfl_xor(s, m, 64);
    float mu = s * 0.00390625f;
    float d0 = v.x - mu, d1 = v.y - mu, d2 = v.z - mu, d3 = v.w - mu;
    float qv = d0 * d0 + d1 * d1 + d2 * d2 + d3 * d3;
#pragma unroll
    for (int m = 1; m < 64; m <<= 1) qv += __shfl_xor(qv, m, 64);
    float rstd = rsqrtf(qv * 0.00390625f + 1e-5f);
    const float4 gg = *(const float4*)&gw[lane * 4];
    const float4 bb = *(const float4*)&bw[lane * 4];
    uint2 u;
    u.x = f2bf(d0 * rstd * gg.x + bb.x) | ((unsigned)f2bf(d1 * rstd * gg.y + bb.y) << 16);
    u.y = f2bf(d2 * rstd * gg.z + bb.z) | ((unsigned)f2bf(d3 * rstd * gg.w + bb.w) << 16);
    *(uint2*)&out[(size_t)row * 256 + lane * 4] = u;
}

// ---------------- fused attention v7 (LDS-staged K/V, 2-phase gl16) ----------------
__global__ __launch_bounds__(256, 4) void attn_kernel(
    const bf16* __restrict__ qh, const bf16* __restrict__ kh,
    const bf16* __restrict__ vt, bf16* __restrict__ obf)
{
    __shared__ alignas(16) bf16 Kl[2][128 * 32];   // [key][chunk g^(key&3)][8]
    __shared__ alignas(16) bf16 Vl[2][32 * 128];   // [d][chunk c^(d&7)][8]
    const int bid = blockIdx.x;
    const int h = bid & 7;                      // XCD-pinned head
    const int tile = bid >> 3;
    const int row0 = tile << 7;                 // 128 queries per block
    const int b = (row0 < 2048) ? 0 : (row0 < 8192) ? 1 : (row0 < 11264) ? 2 : 3;
    const int tid = threadIdx.x, lane = tid & 63, w = tid >> 6;
    const int l15 = lane & 15, g = lane >> 4;
    const int qbase = row0 + (w << 5);          // 32 queries per wave
    const int bh = (b << 3) + h;

    bf16x8 qfA = *(const bf16x8*)&qh[(size_t)(qbase + l15) * 256 + h * 32 + g * 8];
    bf16x8 qfB = *(const bf16x8*)&qh[(size_t)(qbase + 16 + l15) * 256 + h * 32 + g * 8];

    bf16x8 ones;
    {
        unsigned ov = (l15 == 0) ? 0x3f803f80u : 0u;
        unsigned* op = (unsigned*)&ones;
        op[0] = ov; op[1] = ov; op[2] = ov; op[3] = ov;
    }

    f32x4 o0A = {0.f,0.f,0.f,0.f}, o1A = o0A, o2A = o0A;
    f32x4 o0B = o0A, o1B = o0A, o2B = o0A;
    const f32x4 z = {0.f, 0.f, 0.f, 0.f};

    const int skey = lane >> 2;                         // K: key within 16-row group
    const int skc  = (lane & 3) ^ (skey & 3);           //    pre-swizzled chunk
    const int svd  = lane >> 4;                         // V: d within 4-row group
    const int svc  = lane & 15;                         //    chunk (swizzle added per call)
    const bf16* kbase = kh + (size_t)bh * 1024 * 32;
    const bf16* vbase = vt + (size_t)bh * 32 * 1024;

    auto stage = [&](int buf, int kb) {
        if (w < 2) {
#pragma unroll
            for (int jj = 0; jj < 4; ++jj) {
                int j = w * 4 + jj;                     // 16-key group 0..7
                int key = (j << 4) + skey;
                gl16(kbase + (size_t)(kb + key) * 32 + (skc << 3), &Kl[buf][j * 512]);
            }
        } else {
#pragma unroll
            for (int jj = 0; jj < 4; ++jj) {
                int j = (w - 2) * 4 + jj;               // 4-d group 0..7
                int d = (j << 2) + svd;
                gl16(vbase + (size_t)d * 1024 + kb + ((svc ^ (d & 7)) << 3),
                     &Vl[buf][j * 512]);
            }
        }
    };

    stage(0, 0);
    __syncthreads();                     // vmcnt(0) drain + barrier

    const int kc = g ^ (l15 & 3);        // K read chunk (swizzled)
    const int vsw = l15 & 7;             // V read swizzle

    for (int t = 0; t < 8; ++t) {
        const int buf = t & 1;
        if (t < 7) stage(buf ^ 1, (t + 1) << 7);   // next window in flight
#pragma unroll
        for (int s = 0; s < 4; ++s) {
            bf16x8 k0 = *(const bf16x8*)&Kl[buf][((s << 5) + l15) * 32 + (kc << 3)];
            bf16x8 k1 = *(const bf16x8*)&Kl[buf][((s << 5) + 16 + l15) * 32 + (kc << 3)];
            bf16x8 v0 = *(const bf16x8*)&Vl[buf][(l15 << 7) + ((((s << 2) + g) ^ vsw) << 3)];
            bf16x8 v1 = *(const bf16x8*)&Vl[buf][((16 + l15) << 7) + ((((s << 2) + g) ^ vsw) << 3)];

            f32x4 s0A = mfma16(k0, qfA, z);
            f32x4 s1A = mfma16(k1, qfA, z);
            f32x4 s0B = mfma16(k0, qfB, z);
            f32x4 s1B = mfma16(k1, qfB, z);

            uint4 pAu, pBu;
            pAu.x = pk_rtz(ex2(s0A[0]), ex2(s0A[1]));
            pAu.y = pk_rtz(ex2(s0A[2]), ex2(s0A[3]));
            pAu.z = pk_rtz(ex2(s1A[0]), ex2(s1A[1]));
            pAu.w = pk_rtz(ex2(s1A[2]), ex2(s1A[3]));
            pBu.x = pk_rtz(ex2(s0B[0]), ex2(s0B[1]));
            pBu.y = pk_rtz(ex2(s0B[2]), ex2(s0B[3]));
            pBu.z = pk_rtz(ex2(s1B[0]), ex2(s1B[1]));
            pBu.w = pk_rtz(ex2(s1B[2]), ex2(s1B[3]));
            union { uint4 u; bf16x8 v; } cA, cB;
            cA.u = pAu; cB.u = pBu;

            o0A = mfma16(cA.v, v0, o0A);
            o1A = mfma16(cA.v, v1, o1A);
            o2A = mfma16(cA.v, ones, o2A);
            o0B = mfma16(cB.v, v0, o0B);
            o1B = mfma16(cB.v, v1, o1B);
            o2B = mfma16(cB.v, ones, o2B);
        }
        __syncthreads();                 // next window landed; buf reads done
    }

#pragma unroll
    for (int r = 0; r < 4; ++r) {
        float invA = 1.f / __shfl(o2A[r], g << 4, 64);   // denom(q=4g+r) at lane 16g
        float invB = 1.f / __shfl(o2B[r], g << 4, 64);
        size_t orowA = (size_t)(qbase + (g << 2) + r) * 256 + h * 32;
        size_t orowB = (size_t)(qbase + 16 + (g << 2) + r) * 256 + h * 32;
        obf[orowA + l15]      = __float2bfloat16(o0A[r] * invA);
        obf[orowA + 16 + l15] = __float2bfloat16(o1A[r] * invA);
        obf[orowB + l15]      = __float2bfloat16(o0B[r] * invB);
        obf[orowB + 16 + l15] = __float2bfloat16(o1B[r] * invB);
    }
}

// ---------------- launcher ----------------

extern "C" void kernel_launch(void* const* d_in, const int* in_sizes, int n_in,
                              void* d_out, int out_size, void* d_ws, size_t ws_size,
                              hipStream_t stream)
{
    const float* x      = (const float*)d_in[0];
    const float* q      = (const float*)d_in[1];
    const float* w_q    = (const float*)d_in[5];
    const float* w_kv   = (const float*)d_in[6];
    const float* sr_w   = (const float*)d_in[7];
    const float* sr_b   = (const float*)d_in[8];
    const float* ln_g   = (const float*)d_in[9];
    const float* ln_b   = (const float*)d_in[10];
    const float* proj_w = (const float*)d_in[11];
    const float* proj_b = (const float*)d_in[12];

    char* w = (char*)d_ws;
    bf16* xim  = (bf16*)(w + 0);           // 33,554,432  (im2col bf16 [4096][4096])
    bf16* q_bf = (bf16*)(w + 33554432);    //  8,388,608
    bf16* qh   = (bf16*)(w + 41943040);    //  8,388,608
    bf16* wqT  = (bf16*)(w + 50331648);    //    131,072
    bf16* wkvT = (bf16*)(w + 50462720);    //    262,144
    bf16* wprT = (bf16*)(w + 50724864);    //    131,072
    bf16* wcv  = (bf16*)(w + 50855936);    //  2,097,152
    bf16* xln  = (bf16*)(w + 52953088);    //  2,097,152
    bf16* kh   = (bf16*)(w + 55050240);    //  2,097,152  (per-head K [bh][key][32])
    bf16* vt   = (bf16*)(w + 57147392);    //  2,097,152  (per-head V^T, key-permuted)
    bf16* obf  = (bf16*)(w + 59244544);    //  8,388,608
    float* xr  = (float*)(w + 67633152);   //  4,194,304 -> total 71,827,456
    float* out = (float*)d_out;

    transpose_cast_kernel<<<256, 256, 0, stream>>>(w_q, wqT, 256, 256);
    transpose_cast_kernel<<<512, 256, 0, stream>>>(w_kv, wkvT, 256, 512);
    transpose_cast_kernel<<<256, 256, 0, stream>>>(proj_w, wprT, 256, 256);
    conv_w_kernel<<<4096, 256, 0, stream>>>(sr_w, wcv);
    cast_bf16_kernel<<<2048, 256, 0, stream>>>(q, q_bf, 524288);
    im2col_kernel<<<8192, 256, 0, stream>>>(x, xim);

    // q proj -> qh (pre-scaled by SCALE*log2e)
    gemm_kernel<0><<<1024, 256, 0, stream>>>(q_bf, wqT, nullptr, qh, nullptr, nullptr,
                                             16384, 256, 256, 256);
    // conv as GEMM on xim, in-block split-K=4 -> xr f32 (+bias), single write
    conv_gemm_kernel<<<256, 1024, 0, stream>>>(xim, wcv, sr_b, xr);
    // LayerNorm -> xln bf16
    ln_kernel<<<1024, 256, 0, stream>>>(xr, ln_g, ln_b, xln);
    // kv proj -> kh per-head [bh][key][32] and vt (key-permuted) [(b*8+h)*32+d][keyp]
    gemm_kernel<2><<<512, 256, 0, stream>>>(xln, wkvT, nullptr, kh, nullptr, vt,
                                            4096, 512, 256, 256);
    attn_kernel<<<1024, 256, 0, stream>>>(qh, kh, vt, obf);
    // out proj -> d_out (f32, +bias)
    gemm_kernel<1><<<1024, 256, 0, stream>>>(obf, wprT, proj_b, nullptr, out, nullptr,
                                             16384, 256, 256, 256);
}

// Round 12
// 95.334 us; speedup vs baseline: 1.3884x; 1.1488x over previous
//
#include <hip/hip_runtime.h>
#include <hip/hip_bf16.h>

// Pipeline: merged prep (3 weight transposes + conv_w + q cast) -> qproj GEMM ->
//           conv GEMM (DIRECT f32-x im2col gather via per-lane global_load_lds,
//           f32 LDS A-tiles + pk_rtz convert at read, in-block split-K=2) ->
//           LN -> kvproj GEMM -> fused attention (LDS-staged) -> out proj.
// All matmuls + attention use the proven 2-phase __builtin_amdgcn_global_load_lds
// skeleton (DMA state in vmcnt -> immune to regalloc sinking).
// Workspace requirement: ~38 MB.

using bf16 = __hip_bfloat16;
using f32x4 = __attribute__((ext_vector_type(4))) float;
using bf16x8 = __attribute__((ext_vector_type(8))) short;

#define DEVINL __device__ __forceinline__
#define AS1 __attribute__((address_space(1)))
#define AS3 __attribute__((address_space(3)))

DEVINL f32x4 mfma16(bf16x8 a, bf16x8 b, f32x4 c) {
    return __builtin_amdgcn_mfma_f32_16x16x32_bf16(a, b, c, 0, 0, 0);
}

DEVINL unsigned short f2bf(float f) {
    union { float f; unsigned u; } x; x.f = f;
    unsigned u = x.u;
    u += 0x7fffu + ((u >> 16) & 1u);   // RNE
    return (unsigned short)(u >> 16);
}

// pack two f32 -> two bf16 (RTZ) in one v_perm: low16 = trunc(a), high16 = trunc(b)
DEVINL unsigned pk_rtz(float a, float b) {
    return __builtin_amdgcn_perm(__float_as_uint(b), __float_as_uint(a), 0x07060302u);
}

DEVINL float ex2(float x) { return __builtin_amdgcn_exp2f(x); }   // raw v_exp_f32

// async global->LDS DMA, 16B per lane. LDS dest wave-uniform base (HW deposits
// at base + lane*16); GLOBAL source is per-lane (enables gather staging).
DEVINL void gl16(const bf16* g, bf16* l) {
    __builtin_amdgcn_global_load_lds(
        (const AS1 void*)(unsigned long long)(uintptr_t)g,
        (AS3 void*)(unsigned)(uintptr_t)l, 16, 0, 0);
}
DEVINL void gl16f(const float* g, float* l) {
    __builtin_amdgcn_global_load_lds(
        (const AS1 void*)(unsigned long long)(uintptr_t)g,
        (AS3 void*)(unsigned)(uintptr_t)l, 16, 0, 0);
}

// ---------------- merged prep kernel ----------------
// blocks [0,256): w_q transpose; [256,768): w_kv; [768,1024): proj_w;
// [1024,5120): conv weight OIHW->[o][dydx*256+c]; [5120,7168): q f32->bf16.
__global__ __launch_bounds__(256) void prep_kernel(
    const float* __restrict__ w_q, const float* __restrict__ w_kv,
    const float* __restrict__ proj_w, const float* __restrict__ sr_w,
    const float* __restrict__ q,
    bf16* __restrict__ wqT, bf16* __restrict__ wkvT, bf16* __restrict__ wprT,
    bf16* __restrict__ wcv, bf16* __restrict__ q_bf)
{
    const int bb = blockIdx.x;
    if (bb < 256) {
        int idx = bb * 256 + threadIdx.x;
        int k = idx & 255, n = idx >> 8;
        wqT[idx] = __float2bfloat16(w_q[k * 256 + n]);
    } else if (bb < 768) {
        int idx = (bb - 256) * 256 + threadIdx.x;       // K=256, N=512
        int k = idx & 255, n = idx >> 8;
        wkvT[idx] = __float2bfloat16(w_kv[k * 512 + n]);
    } else if (bb < 1024) {
        int idx = (bb - 768) * 256 + threadIdx.x;
        int k = idx & 255, n = idx >> 8;
        wprT[idx] = __float2bfloat16(proj_w[k * 256 + n]);
    } else if (bb < 5120) {
        int idx = (bb - 1024) * 256 + threadIdx.x;      // 1048576
        int o = idx >> 12, rest = idx & 4095, dydx = rest >> 8, c = rest & 255;
        wcv[idx] = __float2bfloat16(sr_w[((o << 8) + c) * 16 + dydx]);
    } else {
        int i = (bb - 5120) * 256 + threadIdx.x;        // 524288 8-elem chunks
        float4 a = ((const float4*)q)[i * 2];
        float4 b = ((const float4*)q)[i * 2 + 1];
        uint4 u;
        u.x = f2bf(a.x) | ((unsigned)f2bf(a.y) << 16);
        u.y = f2bf(a.z) | ((unsigned)f2bf(a.w) << 16);
        u.z = f2bf(b.x) | ((unsigned)f2bf(b.y) << 16);
        u.w = f2bf(b.z) | ((unsigned)f2bf(b.w) << 16);
        ((uint4*)q_bf)[i] = u;
    }
}

// ---------------- GEMM (bf16 A, global_load_lds 2-phase) ----------------
template<int EMODE>
__global__ __launch_bounds__(256, 4) void gemm_kernel(
    const bf16* __restrict__ A, const bf16* __restrict__ WT,
    const float* __restrict__ bias,
    bf16* __restrict__ outb, float* __restrict__ outf, bf16* __restrict__ out2,
    int M, int N, int K, int KS)
{
    __shared__ alignas(16) bf16 As[2][64 * 64];
    __shared__ alignas(16) bf16 Bs[2][64 * 64];
    const int cpx = gridDim.x >> 3;
    const int bx = (blockIdx.x & 7) * cpx + (blockIdx.x >> 3);
    const int ntn = N >> 6;
    const int tm = bx / ntn, tn = bx % ntn;
    const int tid = threadIdx.x, lane = tid & 63, wid = tid >> 6;
    const int l15 = lane & 15, g = lane >> 4;
    const int wm = (wid >> 1) << 5, wn = (wid & 1) << 5;
    f32x4 acc[2][2] = {};

    int r_[2], cs_[2];
#pragma unroll
    for (int j = 0; j < 2; ++j) {
        int idx = (wid * 2 + j) * 64 + lane;
        r_[j] = idx >> 3;
        cs_[j] = ((idx & 7) ^ (r_[j] & 7)) << 3;   // pre-swizzled source column
    }
    const bf16* Arow = &A[(size_t)(tm * 64) * K];
    const bf16* Brow = &WT[(size_t)(tn * 64) * K];

    const int kbeg = blockIdx.y * KS;
    const int nsteps = KS >> 6;

    auto stage = [&](int buf, int k0) {
#pragma unroll
        for (int j = 0; j < 2; ++j) {
            gl16(Arow + (size_t)r_[j] * K + (k0 + cs_[j]), &As[buf][(wid * 2 + j) * 512]);
            gl16(Brow + (size_t)r_[j] * K + (k0 + cs_[j]), &Bs[buf][(wid * 2 + j) * 512]);
        }
    };

    stage(0, kbeg);
    __syncthreads();                     // vmcnt(0) drain + barrier

    for (int t = 0; t < nsteps; ++t) {
        const int buf = t & 1;
        if (t + 1 < nsteps) stage(buf ^ 1, kbeg + (t + 1) * 64);
#pragma unroll
        for (int kk = 0; kk < 2; ++kk) {
            const int sw = l15 & 7;
            const int co = ((kk * 4 + g) ^ sw) << 3;
            bf16x8 a0 = *(const bf16x8*)&As[buf][(wm + l15) * 64 + co];
            bf16x8 a1 = *(const bf16x8*)&As[buf][(wm + 16 + l15) * 64 + co];
            bf16x8 b0 = *(const bf16x8*)&Bs[buf][(wn + l15) * 64 + co];
            bf16x8 b1 = *(const bf16x8*)&Bs[buf][(wn + 16 + l15) * 64 + co];
            acc[0][0] = mfma16(a0, b0, acc[0][0]);
            acc[0][1] = mfma16(a0, b1, acc[0][1]);
            acc[1][0] = mfma16(a1, b0, acc[1][0]);
            acc[1][1] = mfma16(a1, b1, acc[1][1]);
        }
        __syncthreads();
    }

    const float qscale = 0.1767766953f * 1.4426950409f;  // HD^-0.5 * log2(e)
#pragma unroll
    for (int mi = 0; mi < 2; ++mi)
#pragma unroll
    for (int ni = 0; ni < 2; ++ni)
#pragma unroll
    for (int r = 0; r < 4; ++r) {
        int row = tm * 64 + wm + mi * 16 + g * 4 + r;
        int col = tn * 64 + wn + ni * 16 + l15;
        float v = acc[mi][ni][r];
        if constexpr (EMODE == 0) {
            outb[(size_t)row * 256 + col] = __float2bfloat16(v * qscale);
        } else if constexpr (EMODE == 1) {
            outf[(size_t)row * 256 + col] = v + bias[col];
        } else if constexpr (EMODE == 2) {
            int bb = row >> 10, key = row & 1023;
            if (col < 256) {
                int hh = col >> 5, d = col & 31;
                outb[(size_t)(((bb << 3) + hh) * 1024 + key) * 32 + d] = __float2bfloat16(v);
            } else {
                int d = col - 256;
                int c = key & 31;
                int pos = (((c >> 2) & 3) << 3) + ((c >> 4) << 2) + (c & 3);
                int keyp = (key & ~31) | pos;
                out2[(size_t)(((bb << 3) + (d >> 5)) * 32 + (d & 31)) * 1024 + keyp] =
                    __float2bfloat16(v);
            }
        }
    }
}

// ------- conv GEMM: direct f32-x im2col gather, in-block split-K=2 -------
// C[4096,256] = im2col(x)[4096,4096] * wcv[256,4096]^T. 64x64 tile, grid 256,
// 1024 thr = 2 K-groups x 8 waves. A staged as f32 straight from x via
// per-lane-source gl16 (no im2col pass!); converted to bf16 with pk_rtz at
// fragment read (LN downstream is scale-invariant; RTZ noise ~ RNE scale).
// A swizzle: 32B-chunk ^= (row&7) (keeps 8-f32 fragment reads contiguous).
// Partials reduced in LDS, bias added, xr f32 written once.
__global__ __launch_bounds__(1024, 4) void conv_gemm_kernel(
    const float* __restrict__ X, const bf16* __restrict__ WT,
    const float* __restrict__ bias, float* __restrict__ outf)
{
    __shared__ alignas(16) float Af[2][2][64 * 64];   // [grp][buf] f32: 64 KB
    __shared__ alignas(16) bf16 Bs[2][2][64 * 64];    // 32 KB
    const int K = 4096;
    const int bx = (blockIdx.x & 7) * 32 + (blockIdx.x >> 3);   // XCD-chunked
    const int tm = bx >> 2, tn = bx & 3;
    const int tid = threadIdx.x, lane = tid & 63, wid = tid >> 6;
    const int grp = wid >> 3, wg = wid & 7;          // 2 K-groups x 8 waves
    const int l15 = lane & 15, g = lane >> 4;
    const int wm = (wg >> 1) << 4, wn = (wg & 1) << 5;
    f32x4 acc[2] = {};                                // [ni] 16x16 frags

    // A staging lane constants: call j covers tile rows (wg*2+j)*4 .. +3
    size_t laneoffA[2];
#pragma unroll
    for (int j = 0; j < 2; ++j) {
        int rr = (wg * 2 + j) * 4 + (lane >> 4);      // tile-local row
        int pr = tm * 64 + rr;                        // patch index
        int b = pr >> 10, pi = pr & 1023;
        int ii = pi >> 5, jj = pi & 31;
        int c16 = lane & 15;
        int c16s = ((((c16 >> 1) ^ (rr & 7)) << 1) | (c16 & 1));  // src 16B chunk
        laneoffA[j] = ((size_t)((b << 14) + (ii << 2) * 128 + (jj << 2))) * 256
                      + c16s * 4;
    }
    // B staging lane constants (1 call/wave: rows wg*8..+7)
    const int rB = wg * 8 + (lane >> 3);
    const int csB = ((lane & 7) ^ (rB & 7)) << 3;
    const bf16* BrowP = &WT[(size_t)(tn * 64 + rB) * K + csB];

    const int kbeg = grp << 11;                       // 2048 per group

    auto stage = [&](int buf, int t) {
        const int k0 = kbeg + t * 64;
        const int dydx = k0 >> 8;
        const int stepoff = ((dydx >> 2) * 128 + (dydx & 3)) * 256 + (k0 & 255);
#pragma unroll
        for (int j = 0; j < 2; ++j)
            gl16f(X + laneoffA[j] + stepoff, &Af[grp][buf][(wg * 2 + j) * 256]);
        gl16(BrowP + k0, &Bs[grp][buf][wg * 512]);
    };

    stage(0, 0);
    __syncthreads();                     // vmcnt(0) drain + barrier

    for (int t = 0; t < 32; ++t) {
        const int buf = t & 1;
        if (t + 1 < 32) stage(buf ^ 1, t + 1);
#pragma unroll
        for (int kk = 0; kk < 2; ++kk) {
            const int sw = l15 & 7;
            const int uo = ((kk * 4 + g) ^ sw) << 3;  // swizzled 8-elem unit offset
            const float* ap = &Af[grp][buf][(wm + l15) * 64 + uo];
            float4 lo = *(const float4*)ap;
            float4 hi = *(const float4*)(ap + 4);
            uint4 au;
            au.x = pk_rtz(lo.x, lo.y);  au.y = pk_rtz(lo.z, lo.w);
            au.z = pk_rtz(hi.x, hi.y);  au.w = pk_rtz(hi.z, hi.w);
            union { uint4 u; bf16x8 v; } ac; ac.u = au;
            bf16x8 b0 = *(const bf16x8*)&Bs[grp][buf][(wn + l15) * 64 + uo];
            bf16x8 b1 = *(const bf16x8*)&Bs[grp][buf][(wn + 16 + l15) * 64 + uo];
            acc[0] = mfma16(ac.v, b0, acc[0]);
            acc[1] = mfma16(ac.v, b1, acc[1]);
        }
        __syncthreads();
    }

    // ---- reduce the 2 K-group partials in LDS (reuse Af[grp][0]) ----
    {
        float* red = &Af[grp][0][0];
#pragma unroll
        for (int ni = 0; ni < 2; ++ni)
#pragma unroll
        for (int r = 0; r < 4; ++r)
            red[(wm + g * 4 + r) * 64 + wn + ni * 16 + l15] = acc[ni][r];
    }
    __syncthreads();
    {
        const int e = tid << 2;                       // 1024 thr x 4 = 4096
        const float4 s0 = *(const float4*)&Af[0][0][e];
        const float4 s1 = *(const float4*)&Af[1][0][e];
        const int row = e >> 6, col = e & 63;
        const float4 bv = *(const float4*)&bias[tn * 64 + col];
        float4 o;
        o.x = s0.x + s1.x + bv.x;
        o.y = s0.y + s1.y + bv.y;
        o.z = s0.z + s1.z + bv.z;
        o.w = s0.w + s1.w + bv.w;
        *(float4*)&outf[(size_t)(tm * 64 + row) * 256 + tn * 64 + col] = o;
    }
}

// ------- LayerNorm over C=256, one wave per row (bias already applied) -------
__global__ __launch_bounds__(256) void ln_kernel(const float* __restrict__ xr,
                                                 const float* __restrict__ gw,
                                                 const float* __restrict__ bw,
                                                 bf16* __restrict__ out) {
    int row = blockIdx.x * 4 + (threadIdx.x >> 6);
    int lane = threadIdx.x & 63;
    const float4 v = *(const float4*)&xr[(size_t)row * 256 + lane * 4];

    float s = v.x + v.y + v.z + v.w;
#pragma unroll
    for (int m = 1; m < 64; m <<= 1) s += __shfl_xor(s, m, 64);
    float mu = s * 0.00390625f;
    float d0 = v.x - mu, d1 = v.y - mu, d2 = v.z - mu, d3 = v.w - mu;
    float qv = d0 * d0 + d1 * d1 + d2 * d2 + d3 * d3;
#pragma unroll
    for (int m = 1; m < 64; m <<= 1) qv += __shfl_xor(qv, m, 64);
    float rstd = rsqrtf(qv * 0.00390625f + 1e-5f);
    const float4 gg = *(const float4*)&gw[lane * 4];
    const float4 bb = *(const float4*)&bw[lane * 4];
    uint2 u;
    u.x = f2bf(d0 * rstd * gg.x + bb.x) | ((unsigned)f2bf(d1 * rstd * gg.y + bb.y) << 16);
    u.y = f2bf(d2 * rstd * gg.z + bb.z) | ((unsigned)f2bf(d3 * rstd * gg.w + bb.w) << 16);
    *(uint2*)&out[(size_t)row * 256 + lane * 4] = u;
}

// ---------------- fused attention v7 (LDS-staged K/V, 2-phase gl16) ----------------
__global__ __launch_bounds__(256, 4) void attn_kernel(
    const bf16* __restrict__ qh, const bf16* __restrict__ kh,
    const bf16* __restrict__ vt, bf16* __restrict__ obf)
{
    __shared__ alignas(16) bf16 Kl[2][128 * 32];   // [key][chunk g^(key&3)][8]
    __shared__ alignas(16) bf16 Vl[2][32 * 128];   // [d][chunk c^(d&7)][8]
    const int bid = blockIdx.x;
    const int h = bid & 7;                      // XCD-pinned head
    const int tile = bid >> 3;
    const int row0 = tile << 7;                 // 128 queries per block
    const int b = (row0 < 2048) ? 0 : (row0 < 8192) ? 1 : (row0 < 11264) ? 2 : 3;
    const int tid = threadIdx.x, lane = tid & 63, w = tid >> 6;
    const int l15 = lane & 15, g = lane >> 4;
    const int qbase = row0 + (w << 5);          // 32 queries per wave
    const int bh = (b << 3) + h;

    bf16x8 qfA = *(const bf16x8*)&qh[(size_t)(qbase + l15) * 256 + h * 32 + g * 8];
    bf16x8 qfB = *(const bf16x8*)&qh[(size_t)(qbase + 16 + l15) * 256 + h * 32 + g * 8];

    bf16x8 ones;
    {
        unsigned ov = (l15 == 0) ? 0x3f803f80u : 0u;
        unsigned* op = (unsigned*)&ones;
        op[0] = ov; op[1] = ov; op[2] = ov; op[3] = ov;
    }

    f32x4 o0A = {0.f,0.f,0.f,0.f}, o1A = o0A, o2A = o0A;
    f32x4 o0B = o0A, o1B = o0A, o2B = o0A;
    const f32x4 z = {0.f, 0.f, 0.f, 0.f};

    const int skey = lane >> 2;                         // K: key within 16-row group
    const int skc  = (lane & 3) ^ (skey & 3);           //    pre-swizzled chunk
    const int svd  = lane >> 4;                         // V: d within 4-row group
    const int svc  = lane & 15;                         //    chunk (swizzle per call)
    const bf16* kbase = kh + (size_t)bh * 1024 * 32;
    const bf16* vbase = vt + (size_t)bh * 32 * 1024;

    auto stage = [&](int buf, int kb) {
        if (w < 2) {
#pragma unroll
            for (int jj = 0; jj < 4; ++jj) {
                int j = w * 4 + jj;
                int key = (j << 4) + skey;
                gl16(kbase + (size_t)(kb + key) * 32 + (skc << 3), &Kl[buf][j * 512]);
            }
        } else {
#pragma unroll
            for (int jj = 0; jj < 4; ++jj) {
                int j = (w - 2) * 4 + jj;
                int d = (j << 2) + svd;
                gl16(vbase + (size_t)d * 1024 + kb + ((svc ^ (d & 7)) << 3),
                     &Vl[buf][j * 512]);
            }
        }
    };

    stage(0, 0);
    __syncthreads();

    const int kc = g ^ (l15 & 3);        // K read chunk (swizzled)
    const int vsw = l15 & 7;             // V read swizzle

    for (int t = 0; t < 8; ++t) {
        const int buf = t & 1;
        if (t < 7) stage(buf ^ 1, (t + 1) << 7);
#pragma unroll
        for (int s = 0; s < 4; ++s) {
            bf16x8 k0 = *(const bf16x8*)&Kl[buf][((s << 5) + l15) * 32 + (kc << 3)];
            bf16x8 k1 = *(const bf16x8*)&Kl[buf][((s << 5) + 16 + l15) * 32 + (kc << 3)];
            bf16x8 v0 = *(const bf16x8*)&Vl[buf][(l15 << 7) + ((((s << 2) + g) ^ vsw) << 3)];
            bf16x8 v1 = *(const bf16x8*)&Vl[buf][((16 + l15) << 7) + ((((s << 2) + g) ^ vsw) << 3)];

            f32x4 s0A = mfma16(k0, qfA, z);
            f32x4 s1A = mfma16(k1, qfA, z);
            f32x4 s0B = mfma16(k0, qfB, z);
            f32x4 s1B = mfma16(k1, qfB, z);

            uint4 pAu, pBu;
            pAu.x = pk_rtz(ex2(s0A[0]), ex2(s0A[1]));
            pAu.y = pk_rtz(ex2(s0A[2]), ex2(s0A[3]));
            pAu.z = pk_rtz(ex2(s1A[0]), ex2(s1A[1]));
            pAu.w = pk_rtz(ex2(s1A[2]), ex2(s1A[3]));
            pBu.x = pk_rtz(ex2(s0B[0]), ex2(s0B[1]));
            pBu.y = pk_rtz(ex2(s0B[2]), ex2(s0B[3]));
            pBu.z = pk_rtz(ex2(s1B[0]), ex2(s1B[1]));
            pBu.w = pk_rtz(ex2(s1B[2]), ex2(s1B[3]));
            union { uint4 u; bf16x8 v; } cA, cB;
            cA.u = pAu; cB.u = pBu;

            o0A = mfma16(cA.v, v0, o0A);
            o1A = mfma16(cA.v, v1, o1A);
            o2A = mfma16(cA.v, ones, o2A);
            o0B = mfma16(cB.v, v0, o0B);
            o1B = mfma16(cB.v, v1, o1B);
            o2B = mfma16(cB.v, ones, o2B);
        }
        __syncthreads();
    }

#pragma unroll
    for (int r = 0; r < 4; ++r) {
        float invA = 1.f / __shfl(o2A[r], g << 4, 64);
        float invB = 1.f / __shfl(o2B[r], g << 4, 64);
        size_t orowA = (size_t)(qbase + (g << 2) + r) * 256 + h * 32;
        size_t orowB = (size_t)(qbase + 16 + (g << 2) + r) * 256 + h * 32;
        obf[orowA + l15]      = __float2bfloat16(o0A[r] * invA);
        obf[orowA + 16 + l15] = __float2bfloat16(o1A[r] * invA);
        obf[orowB + l15]      = __float2bfloat16(o0B[r] * invB);
        obf[orowB + 16 + l15] = __float2bfloat16(o1B[r] * invB);
    }
}

// ---------------- launcher ----------------

extern "C" void kernel_launch(void* const* d_in, const int* in_sizes, int n_in,
                              void* d_out, int out_size, void* d_ws, size_t ws_size,
                              hipStream_t stream)
{
    const float* x      = (const float*)d_in[0];
    const float* q      = (const float*)d_in[1];
    const float* w_q    = (const float*)d_in[5];
    const float* w_kv   = (const float*)d_in[6];
    const float* sr_w   = (const float*)d_in[7];
    const float* sr_b   = (const float*)d_in[8];
    const float* ln_g   = (const float*)d_in[9];
    const float* ln_b   = (const float*)d_in[10];
    const float* proj_w = (const float*)d_in[11];
    const float* proj_b = (const float*)d_in[12];

    char* w = (char*)d_ws;
    bf16* q_bf = (bf16*)(w + 0);           //  8,388,608
    bf16* qh   = (bf16*)(w + 8388608);     //  8,388,608
    bf16* wqT  = (bf16*)(w + 16777216);    //    131,072
    bf16* wkvT = (bf16*)(w + 16908288);    //    262,144
    bf16* wprT = (bf16*)(w + 17170432);    //    131,072
    bf16* wcv  = (bf16*)(w + 17301504);    //  2,097,152
    bf16* xln  = (bf16*)(w + 19398656);    //  2,097,152
    bf16* kh   = (bf16*)(w + 21495808);    //  2,097,152  (per-head K [bh][key][32])
    bf16* vt   = (bf16*)(w + 23592960);    //  2,097,152  (per-head V^T, key-permuted)
    bf16* obf  = (bf16*)(w + 25690112);    //  8,388,608
    float* xr  = (float*)(w + 34078720);   //  4,194,304 -> total 38,273,024
    float* out = (float*)d_out;

    // merged prep: 3 weight transposes + conv weight reorder + q cast
    prep_kernel<<<7168, 256, 0, stream>>>(w_q, w_kv, proj_w, sr_w, q,
                                          wqT, wkvT, wprT, wcv, q_bf);
    // q proj -> qh (pre-scaled by SCALE*log2e)
    gemm_kernel<0><<<1024, 256, 0, stream>>>(q_bf, wqT, nullptr, qh, nullptr, nullptr,
                                             16384, 256, 256, 256);
    // conv: direct f32-x im2col gather, in-block split-K=2 -> xr f32 (+bias)
    conv_gemm_kernel<<<256, 1024, 0, stream>>>(x, wcv, sr_b, xr);
    // LayerNorm -> xln bf16
    ln_kernel<<<1024, 256, 0, stream>>>(xr, ln_g, ln_b, xln);
    // kv proj -> kh per-head [bh][key][32] and vt (key-permuted)
    gemm_kernel<2><<<512, 256, 0, stream>>>(xln, wkvT, nullptr, kh, nullptr, vt,
                                            4096, 512, 256, 256);
    attn_kernel<<<1024, 256, 0, stream>>>(qh, kh, vt, obf);
    // out proj -> d_out (f32, +bias)
    gemm_kernel<1><<<1024, 256, 0, stream>>>(obf, wprT, proj_b, nullptr, out, nullptr,
                                             16384, 256, 256, 256);
}